// Round 2
// baseline (147.252 us; speedup 1.0000x reference)
//
#include <hip/hip_runtime.h>

typedef __bf16   bf16x8 __attribute__((ext_vector_type(8)));
typedef float    f32x4  __attribute__((ext_vector_type(4)));
typedef float    f32x2  __attribute__((ext_vector_type(2)));
typedef uint32_t u32x4  __attribute__((ext_vector_type(4)));

constexpr int N_ = 16384;
constexpr int D_ = 16;
constexpr int P_ = 8;
constexpr int H_ = 128;
constexpr int M_ = 50;

// pack two f32 -> one bf16x2 register word (round-half-up; 3 VALU ops)
__device__ __forceinline__ uint32_t pk_bf16(float a, float b) {
    uint32_t ua = __builtin_bit_cast(uint32_t, a) + 0x8000u;
    uint32_t ub = __builtin_bit_cast(uint32_t, b) + 0x8000u;
    return __builtin_amdgcn_perm(ub, ua, 0x07060302u);   // [a.hi16 | b.hi16]
}
__device__ __forceinline__ uint32_t pk_relu_bf16(float a, float b) {
    return pk_bf16(fmaxf(a, 0.0f), fmaxf(b, 0.0f));
}

// R5 == R4 resubmit (R4 bench was an infra failure, no counters returned).
// 2-wave cooperative split of the hidden dimension. Each block = 2 waves
// handling the SAME 16 particles; wave wv owns output tiles ct in
// [4*wv, 4*wv+4) of layers 1-2 (halves the weight registers: ~190 VGPR/wave,
// fits 2 waves/SIMD) and the two packed B-fragments kt = {2wv, 2wv+1}.
// Halves of h1/h2 are exchanged via an LDS ping-pong buffer (lane-aligned,
// conflict-free b128). Layer 3 + X/V update are replicated in both waves
// (4 MFMA + ~35 VALU) to avoid a third exchange. Raw s_barrier + manual
// lgkmcnt(0) (NOT __syncthreads) so the distance-2 noise prefetch keeps its
// vmcnt in flight across the 2 barriers/step.
// Slot s -> global kt mapping (s0,s1 = own frags, s2,s3 = partner's) is baked
// into the A-operand weight fragments at load time; the K-sum is
// order-independent so no renumbering is needed after the exchange.
__global__ __launch_bounds__(128, 2)
void sde_fused(const float* __restrict__ X0,
               const float* __restrict__ V0,
               const float* __restrict__ Yobs,
               const float* __restrict__ noise,
               const float* __restrict__ W1, const float* __restrict__ b1,
               const float* __restrict__ W2, const float* __restrict__ b2,
               const float* __restrict__ W3, const float* __restrict__ b3,
               float* __restrict__ out)
{
    const int tid  = threadIdx.x;
    const int lane = tid & 63;
    const int wv   = tid >> 6;           // 0 or 1: which half of H this wave owns
    const int n    = lane & 15;
    const int q    = lane >> 4;
    const int gr   = blockIdx.x * 16 + n;

    const int ct0 = wv * 4;              // own output ct tiles: ct0..ct0+3

    const float dt   = 0.02f;
    const float sqdt = 0.1414213562373095f;

    // ---- weight fragments, A-operand layout A[m=lane&15][k=q*8+j] ----
    // layer 1: own 4 ct tiles only
    bf16x8 w1f[4];
#pragma unroll
    for (int c = 0; c < 4; ++c) {
        const int ct = ct0 + c;
        u32x4 u;
        u[0] = pk_bf16(W1[(1 + q * 4 + 0) * H_ + ct * 16 + n],
                       W1[(1 + q * 4 + 1) * H_ + ct * 16 + n]);
        u[1] = pk_bf16(W1[(1 + q * 4 + 2) * H_ + ct * 16 + n],
                       W1[(1 + q * 4 + 3) * H_ + ct * 16 + n]);
        u[2] = pk_bf16(W1[(17 + q * 2 + 0) * H_ + ct * 16 + n],
                       W1[(17 + q * 2 + 1) * H_ + ct * 16 + n]);
        u[3] = (q == 0) ? pk_bf16(b1[ct * 16 + n], W1[ct * 16 + n]) : 0u;
        w1f[c] = __builtin_bit_cast(bf16x8, u);
    }
    // layer 2: own 4 ct tiles x 4 K-slots; slot s -> global kt g
    bf16x8 w2f[4][4];
#pragma unroll
    for (int cc = 0; cc < 4; ++cc) {
        const int ct = ct0 + cc;
#pragma unroll
        for (int s = 0; s < 4; ++s) {
            const int g = (s < 2) ? (2 * wv + s) : (2 * (wv ^ 1) + (s - 2));
            u32x4 u;
#pragma unroll
            for (int w = 0; w < 4; ++w) {
                int h0 = (g * 2 + (w >> 1)) * 16 + q * 4 + (w & 1) * 2;
                u[w] = pk_bf16(W2[h0 * H_ + ct * 16 + n],
                               W2[(h0 + 1) * H_ + ct * 16 + n]);
            }
            w2f[cc][s] = __builtin_bit_cast(bf16x8, u);
        }
    }
    // layer 3: full (replicated), same slot ordering as the h2 fragments
    bf16x8 w3f[4];
#pragma unroll
    for (int s = 0; s < 4; ++s) {
        const int g = (s < 2) ? (2 * wv + s) : (2 * (wv ^ 1) + (s - 2));
        u32x4 u;
#pragma unroll
        for (int w = 0; w < 4; ++w) {
            int h0 = (g * 2 + (w >> 1)) * 16 + q * 4 + (w & 1) * 2;
            u[w] = pk_bf16(W3[h0 * D_ + n], W3[(h0 + 1) * D_ + n]);
        }
        w3f[s] = __builtin_bit_cast(bf16x8, u);
    }
    f32x4 b2r[4];
#pragma unroll
    for (int cc = 0; cc < 4; ++cc)
#pragma unroll
        for (int r = 0; r < 4; ++r) b2r[cc][r] = b2[(ct0 + cc) * 16 + q * 4 + r];
    f32x4 b3r;
#pragma unroll
    for (int r = 0; r < 4; ++r) b3r[r] = b3[q * 4 + r];

    // ---- LDS exchange buffers: [buf h1/h2][wave][frag][lane], 8 KB ----
    __shared__ bf16x8 xch[2][2][2][64];

    // ---- state (replicated in both waves; identical arithmetic keeps x in sync) ----
    f32x4 x = *(const f32x4*)&X0[gr * D_ + q * 4];
    f32x2 y2 = *(const f32x2*)&Yobs[gr * P_ + q * 2];
    const uint32_t yw = pk_bf16(y2[0], y2[1]);   // constant word2 of a0

    const float* npb = noise + (size_t)gr * D_ + q * 4;
    f32x4 e0 = *(const f32x4*)npb;
    f32x4 e1 = *(const f32x4*)(npb + (size_t)N_ * D_);
    float t = 0.0f;
    float vacc = 0.0f;   // per-lane V partial, reduced once after the loop

    for (int m = 0; m < M_; ++m) {
        int mp = (m + 2 < M_) ? (m + 2) : (M_ - 1);
        f32x4 e2 = *(const f32x4*)(npb + (size_t)mp * N_ * D_);

        // ---- layer 1 B fragment: [X(4) | Y(2) | one | t] ----
        u32x4 au;
        au[0] = pk_bf16(x[0], x[1]);
        au[1] = pk_bf16(x[2], x[3]);
        au[2] = yw;
        au[3] = (q == 0) ? pk_bf16(1.0f, t) : 0u;
        bf16x8 a0 = __builtin_bit_cast(bf16x8, au);

        // ---- layer 1: own 4 ct tiles ----
        f32x4 h1c[4];
#pragma unroll
        for (int c = 0; c < 4; ++c)
            h1c[c] = __builtin_amdgcn_mfma_f32_16x16x32_bf16(
                w1f[c], a0, (f32x4){0.f, 0.f, 0.f, 0.f}, 0, 0, 0);

        // pack own two B-fragments (global kt = 2wv, 2wv+1)
        bf16x8 my0, my1;
        {
            u32x4 u;
            u[0] = pk_relu_bf16(h1c[0][0], h1c[0][1]);
            u[1] = pk_relu_bf16(h1c[0][2], h1c[0][3]);
            u[2] = pk_relu_bf16(h1c[1][0], h1c[1][1]);
            u[3] = pk_relu_bf16(h1c[1][2], h1c[1][3]);
            my0 = __builtin_bit_cast(bf16x8, u);
        }
        {
            u32x4 u;
            u[0] = pk_relu_bf16(h1c[2][0], h1c[2][1]);
            u[1] = pk_relu_bf16(h1c[2][2], h1c[2][3]);
            u[2] = pk_relu_bf16(h1c[3][0], h1c[3][1]);
            u[3] = pk_relu_bf16(h1c[3][2], h1c[3][3]);
            my1 = __builtin_bit_cast(bf16x8, u);
        }

        // ---- exchange h1 halves (buffer 0) ----
        xch[0][wv][0][lane] = my0;
        xch[0][wv][1][lane] = my1;
        asm volatile("s_waitcnt lgkmcnt(0)" ::: "memory");
        __builtin_amdgcn_s_barrier();
        __builtin_amdgcn_sched_barrier(0);
        bf16x8 ot0 = xch[0][wv ^ 1][0][lane];
        bf16x8 ot1 = xch[0][wv ^ 1][1][lane];

        // ---- layer 2: own 4 output tiles, K-sum over 4 slots ----
        f32x4 h2c[4];
#pragma unroll
        for (int cc = 0; cc < 4; ++cc) {
            f32x4 c = b2r[cc];
            c = __builtin_amdgcn_mfma_f32_16x16x32_bf16(w2f[cc][0], my0, c, 0, 0, 0);
            c = __builtin_amdgcn_mfma_f32_16x16x32_bf16(w2f[cc][1], my1, c, 0, 0, 0);
            c = __builtin_amdgcn_mfma_f32_16x16x32_bf16(w2f[cc][2], ot0, c, 0, 0, 0);
            c = __builtin_amdgcn_mfma_f32_16x16x32_bf16(w2f[cc][3], ot1, c, 0, 0, 0);
            h2c[cc] = c;
        }

        bf16x8 m20, m21;
        {
            u32x4 u;
            u[0] = pk_relu_bf16(h2c[0][0], h2c[0][1]);
            u[1] = pk_relu_bf16(h2c[0][2], h2c[0][3]);
            u[2] = pk_relu_bf16(h2c[1][0], h2c[1][1]);
            u[3] = pk_relu_bf16(h2c[1][2], h2c[1][3]);
            m20 = __builtin_bit_cast(bf16x8, u);
        }
        {
            u32x4 u;
            u[0] = pk_relu_bf16(h2c[2][0], h2c[2][1]);
            u[1] = pk_relu_bf16(h2c[2][2], h2c[2][3]);
            u[2] = pk_relu_bf16(h2c[3][0], h2c[3][1]);
            u[3] = pk_relu_bf16(h2c[3][2], h2c[3][3]);
            m21 = __builtin_bit_cast(bf16x8, u);
        }

        // ---- exchange h2 halves (buffer 1) ----
        xch[1][wv][0][lane] = m20;
        xch[1][wv][1][lane] = m21;
        asm volatile("s_waitcnt lgkmcnt(0)" ::: "memory");
        __builtin_amdgcn_s_barrier();
        __builtin_amdgcn_sched_barrier(0);
        bf16x8 o20 = xch[1][wv ^ 1][0][lane];
        bf16x8 o21 = xch[1][wv ^ 1][1][lane];

        // ---- layer 3: replicated (z order differs per wave; only feeds V,
        //      and only wave 0's V is stored — X update is z-independent) ----
        f32x4 za = __builtin_amdgcn_mfma_f32_16x16x32_bf16(w3f[0], m20, b3r, 0, 0, 0);
        za = __builtin_amdgcn_mfma_f32_16x16x32_bf16(w3f[1], m21, za, 0, 0, 0);
        f32x4 zb = __builtin_amdgcn_mfma_f32_16x16x32_bf16(
            w3f[2], o20, (f32x4){0.f, 0.f, 0.f, 0.f}, 0, 0, 0);
        zb = __builtin_amdgcn_mfma_f32_16x16x32_bf16(w3f[3], o21, zb, 0, 0, 0);

        // ---- V partial + X update (no cross-lane work in the loop) ----
#pragma unroll
        for (int r = 0; r < 4; ++r) {
            float z  = za[r] + zb[r];
            float wn = sqdt * e0[r];
            vacc = fmaf(z, wn, fmaf(0.01f * z, z, vacc));   // z*wn + dt/2*z^2
            x[r] = fmaf(x[r], 0.98f, wn);                   // (1-dt)*x + wn
        }

        e0 = e1; e1 = e2;
        t += dt;
    }

    // ---- final V reduction across the 4 q-groups; wave 0 stores ----
    float part = vacc;
    part += __shfl_xor(part, 16);
    part += __shfl_xor(part, 32);

    if (wv == 0) {
        *(f32x4*)&out[gr * D_ + q * 4] = x;
        if (q == 0) out[N_ * D_ + gr] = V0[gr] + part;
    }
}

extern "C" void kernel_launch(void* const* d_in, const int* in_sizes, int n_in,
                              void* d_out, int out_size, void* d_ws, size_t ws_size,
                              hipStream_t stream)
{
    const float* X0 = (const float*)d_in[0];
    const float* V0 = (const float*)d_in[1];
    const float* Y  = (const float*)d_in[2];
    const float* nz = (const float*)d_in[3];
    const float* W1 = (const float*)d_in[4];
    const float* b1 = (const float*)d_in[5];
    const float* W2 = (const float*)d_in[6];
    const float* b2 = (const float*)d_in[7];
    const float* W3 = (const float*)d_in[8];
    const float* b3 = (const float*)d_in[9];
    float* out = (float*)d_out;

    sde_fused<<<N_ / 16, 128, 0, stream>>>(X0, V0, Y, nz, W1, b1, W2, b2, W3, b3, out);
}